// Round 1
// baseline (449.044 us; speedup 1.0000x reference)
//
#include <hip/hip_runtime.h>
#include <cstdint>
#include <cstddef>

// ---------- types ----------
typedef __attribute__((ext_vector_type(8))) short short8;   // 8 bf16 (4 VGPRs)
typedef __attribute__((ext_vector_type(4))) short short4v;  // 4 bf16
typedef __attribute__((ext_vector_type(4))) float f32x4;    // MFMA accum

__device__ __forceinline__ short f2bf(float f) {
    union { float f; unsigned u; } c; c.f = f;
    unsigned r = c.u + 0x7fffu + ((c.u >> 16) & 1u);   // RNE
    return (short)(r >> 16);
}

// ---------- 1. weight convert/transpose (bf16), fold q scale into Wq ----------
__global__ __launch_bounds__(256) void conv_weights(
    const float* __restrict__ Wq, const float* __restrict__ Wkv, const float* __restrict__ Wo,
    short* __restrict__ WqT, short* __restrict__ WkvT, short* __restrict__ WoT)
{
    int idx = blockIdx.x * 256 + threadIdx.x;
    if (idx < 1024 * 1024) {                       // WkvT: (N=1024, K=1024)
        int n = idx >> 10, k = idx & 1023;
        WkvT[idx] = f2bf(Wkv[k * 1024 + n]);
    } else if (idx < 1024 * 1024 + 512 * 1024) {   // WqT: (N=512, K=1024), * dh^-0.5
        int j = idx - 1024 * 1024;
        int n = j >> 10, k = j & 1023;
        WqT[j] = f2bf(Wq[k * 512 + n] * 0.125f);
    } else {                                       // WoT: (N=1024, K=512)
        int j = idx - (1024 * 1024 + 512 * 1024);
        int n = j >> 9, k = j & 511;
        WoT[j] = f2bf(Wo[k * 1024 + n]);
    }
}

// ---------- 2. LayerNorm -> bf16; builds kv_in = concat(xn, ln) per bt ----------
// rows 0..32767: x rows (bt = blk/2048, i = blk%2048) -> A[bt*2112 + i]
// rows 32768..33791: latent rows -> A[bt*2112 + 2048 + i], also -> Lq (contiguous)
__global__ __launch_bounds__(256) void ln_kernel(
    const float* __restrict__ x, const float* __restrict__ lat,
    const float* __restrict__ gx, const float* __restrict__ bx,
    const float* __restrict__ gl, const float* __restrict__ bl,
    short* __restrict__ Aout, short* __restrict__ Lq)
{
    const int blk = blockIdx.x;
    const int tid = threadIdx.x;
    const float *src, *g, *b; size_t drow; short* dst2 = nullptr;
    if (blk < 32768) {
        int bt = blk >> 11, i = blk & 2047;
        src = x + (size_t)blk * 1024; g = gx; b = bx;
        drow = (size_t)bt * 2112 + i;
    } else {
        int idx = blk - 32768;
        int bt = idx >> 6, i = idx & 63;
        src = lat + (size_t)idx * 1024; g = gl; b = bl;
        drow = (size_t)bt * 2112 + 2048 + i;
        dst2 = Lq + (size_t)idx * 1024;
    }
    float4 v = ((const float4*)src)[tid];
    float s  = v.x + v.y + v.z + v.w;
    float s2 = v.x * v.x + v.y * v.y + v.z * v.z + v.w * v.w;
    for (int off = 32; off >= 1; off >>= 1) { s += __shfl_down(s, off); s2 += __shfl_down(s2, off); }
    __shared__ float red[8];
    const int wv = tid >> 6, ln_ = tid & 63;
    if (ln_ == 0) { red[wv] = s; red[4 + wv] = s2; }
    __syncthreads();
    s  = red[0] + red[1] + red[2] + red[3];
    s2 = red[4] + red[5] + red[6] + red[7];
    const float mu   = s * (1.f / 1024.f);
    const float var  = s2 * (1.f / 1024.f) - mu * mu;
    const float rstd = rsqrtf(var + 1e-5f);
    float4 gv = ((const float4*)g)[tid];
    float4 bv = ((const float4*)b)[tid];
    short4v o;
    o[0] = f2bf((v.x - mu) * rstd * gv.x + bv.x);
    o[1] = f2bf((v.y - mu) * rstd * gv.y + bv.y);
    o[2] = f2bf((v.z - mu) * rstd * gv.z + bv.z);
    o[3] = f2bf((v.w - mu) * rstd * gv.w + bv.w);
    *(short4v*)(Aout + drow * 1024 + tid * 4) = o;
    if (dst2) *(short4v*)(dst2 + tid * 4) = o;
}

// ---------- 3. bf16 GEMM, C = A(MxK) * Bt(NxK)^T, 128x128 tile, 4 waves ----------
template <typename OutT>
__global__ __launch_bounds__(256) void gemm_bt(
    const short* __restrict__ A, const short* __restrict__ Bt,
    OutT* __restrict__ C, int M, int N, int K)
{
    __shared__ short As[128 * 32];
    __shared__ short Bs[128 * 32];
    const int tid  = threadIdx.x;
    const int wave = tid >> 6, lane = tid & 63;
    const int col  = lane & 15, quad = lane >> 4;
    const int m0 = blockIdx.x * 128, n0 = blockIdx.y * 128;
    const int wm = (wave >> 1) * 64, wn = (wave & 1) * 64;
    const int sr = tid >> 2;           // staging row 0..63
    const int sk = (tid & 3) * 8;      // staging k offset

    f32x4 acc[4][4];
    for (int i = 0; i < 4; i++) for (int j = 0; j < 4; j++) acc[i][j] = f32x4{0.f, 0.f, 0.f, 0.f};

    const short* Ar0 = A  + (size_t)(m0 + sr)      * K + sk;
    const short* Ar1 = A  + (size_t)(m0 + sr + 64) * K + sk;
    const short* Br0 = Bt + (size_t)(n0 + sr)      * K + sk;
    const short* Br1 = Bt + (size_t)(n0 + sr + 64) * K + sk;

    for (int k0 = 0; k0 < K; k0 += 32) {
        __syncthreads();
        *(short8*)&As[sr * 32 + sk]        = *(const short8*)(Ar0 + k0);
        *(short8*)&As[(sr + 64) * 32 + sk] = *(const short8*)(Ar1 + k0);
        *(short8*)&Bs[sr * 32 + sk]        = *(const short8*)(Br0 + k0);
        *(short8*)&Bs[(sr + 64) * 32 + sk] = *(const short8*)(Br1 + k0);
        __syncthreads();
        short8 af[4], bf[4];
        for (int mt = 0; mt < 4; mt++) af[mt] = *(const short8*)&As[(wm + mt * 16 + col) * 32 + quad * 8];
        for (int nt = 0; nt < 4; nt++) bf[nt] = *(const short8*)&Bs[(wn + nt * 16 + col) * 32 + quad * 8];
        for (int mt = 0; mt < 4; mt++)
            for (int nt = 0; nt < 4; nt++)
                acc[mt][nt] = __builtin_amdgcn_mfma_f32_16x16x32_bf16(af[mt], bf[nt], acc[mt][nt], 0, 0, 0);
    }
    for (int mt = 0; mt < 4; mt++)
        for (int nt = 0; nt < 4; nt++)
            for (int r = 0; r < 4; r++) {
                int row = m0 + wm + mt * 16 + quad * 4 + r;
                int cc  = n0 + wn + nt * 16 + col;
                float v = acc[mt][nt][r];
                if constexpr (sizeof(OutT) == 2) C[(size_t)row * N + cc] = (OutT)f2bf(v);
                else                             C[(size_t)row * N + cc] = v;
            }
}

// ---------- 4. transpose V: KV[bt*2112+j][512+h*64+d] -> Vt[(bt*8+h)*64+d][j] ----------
__global__ __launch_bounds__(256) void transpose_v(const short* __restrict__ KV, short* __restrict__ Vt)
{
    __shared__ short tile[32][33];
    const int bth = blockIdx.z, bt = bth >> 3, h = bth & 7;
    const int jt = blockIdx.x * 32, dt = blockIdx.y * 32;
    const int x = threadIdx.x, y = threadIdx.y;   // (32, 8)
    for (int yy = y; yy < 32; yy += 8)
        tile[yy][x] = KV[(size_t)(bt * 2112 + jt + yy) * 1024 + 512 + h * 64 + dt + x];
    __syncthreads();
    for (int yy = y; yy < 32; yy += 8)
        Vt[(size_t)(bth * 64 + dt + yy) * 2112 + jt + x] = tile[x][yy];
}

// ---------- 5. attention: one WG per (bt,h); 4 waves, online softmax ----------
__global__ __launch_bounds__(256) void attn_kernel(
    const short* __restrict__ Q,    // (1024, 512)  rows bt*64+i, cols h*64+d
    const short* __restrict__ KV,   // (33792, 1024) k in cols 0..511
    const short* __restrict__ Vt,   // (128*64, 2112)
    short* __restrict__ AttO)       // (1024, 512)
{
    __shared__ short p_lds[4][64 * 72];   // per-wave P buffer, pitch 72 (144B, 16B-mult)
    __shared__ float sm[4][64];
    __shared__ float sl[4][64];
    __shared__ float oacc[64 * 64];

    const int wg = blockIdx.x;            // 0..127 = bt*8 + h
    const int bt = wg >> 3, h = wg & 7;
    const int tid = threadIdx.x;
    const int wave = tid >> 6, lane = tid & 63;
    const int col = lane & 15, quad = lane >> 4;

    // preload Q A-fragments (scale already folded into Wq)
    short8 qf[4][2];
    for (int mt = 0; mt < 4; mt++)
        for (int ks = 0; ks < 2; ks++)
            qf[mt][ks] = *(const short8*)(Q + (size_t)(bt * 64 + mt * 16 + col) * 512
                                            + h * 64 + ks * 32 + quad * 8);

    float m_run[4][4], l_run[4][4];
    f32x4 o_acc[4][4];
    for (int mt = 0; mt < 4; mt++)
        for (int r = 0; r < 4; r++) { m_run[mt][r] = -__builtin_inff(); l_run[mt][r] = 0.f; }
    for (int mt = 0; mt < 4; mt++)
        for (int dt = 0; dt < 4; dt++) o_acc[mt][dt] = f32x4{0.f, 0.f, 0.f, 0.f};

    short* pl = p_lds[wave];

    for (int jb = wave; jb < 33; jb += 4) {          // 2112 keys = 33 blocks of 64
        // ---- S = Q K^T (64 x 64) ----
        f32x4 s[4][4];
        for (int mt = 0; mt < 4; mt++) for (int nt = 0; nt < 4; nt++) s[mt][nt] = f32x4{0.f, 0.f, 0.f, 0.f};
        for (int nt = 0; nt < 4; nt++) {
            const int j = jb * 64 + nt * 16 + col;
            const short* kp = KV + (size_t)(bt * 2112 + j) * 1024 + h * 64 + quad * 8;
            short8 k0 = *(const short8*)kp;
            short8 k1 = *(const short8*)(kp + 32);
            for (int mt = 0; mt < 4; mt++) {
                s[mt][nt] = __builtin_amdgcn_mfma_f32_16x16x32_bf16(qf[mt][0], k0, s[mt][nt], 0, 0, 0);
                s[mt][nt] = __builtin_amdgcn_mfma_f32_16x16x32_bf16(qf[mt][1], k1, s[mt][nt], 0, 0, 0);
            }
        }
        // ---- online softmax (per row: row = mt*16 + quad*4 + r) ----
        for (int mt = 0; mt < 4; mt++)
            for (int r = 0; r < 4; r++) {
                float mx = fmaxf(fmaxf(s[mt][0][r], s[mt][1][r]), fmaxf(s[mt][2][r], s[mt][3][r]));
                for (int off = 8; off >= 1; off >>= 1) mx = fmaxf(mx, __shfl_xor(mx, off));
                float mnew = fmaxf(m_run[mt][r], mx);
                float alpha = __expf(m_run[mt][r] - mnew);
                float rs = 0.f;
                for (int nt = 0; nt < 4; nt++) {
                    float p = __expf(s[mt][nt][r] - mnew);
                    s[mt][nt][r] = p;
                    rs += p;
                }
                for (int off = 8; off >= 1; off >>= 1) rs += __shfl_xor(rs, off);
                m_run[mt][r] = mnew;
                l_run[mt][r] = l_run[mt][r] * alpha + rs;
                for (int dt = 0; dt < 4; dt++) o_acc[mt][dt][r] *= alpha;
            }
        // ---- P: C-layout -> LDS row-major [m][72] ----
        for (int mt = 0; mt < 4; mt++)
            for (int nt = 0; nt < 4; nt++)
                for (int r = 0; r < 4; r++)
                    pl[(mt * 16 + quad * 4 + r) * 72 + nt * 16 + col] = f2bf(s[mt][nt][r]);
        // ---- O += P V ----
        for (int ks = 0; ks < 2; ks++) {
            short8 vf[4];
            for (int dt = 0; dt < 4; dt++)
                vf[dt] = *(const short8*)(Vt + (size_t)(wg * 64 + dt * 16 + col) * 2112
                                             + jb * 64 + ks * 32 + quad * 8);
            for (int mt = 0; mt < 4; mt++) {
                short8 pf = *(const short8*)(pl + (mt * 16 + col) * 72 + ks * 32 + quad * 8);
                for (int dt = 0; dt < 4; dt++)
                    o_acc[mt][dt] = __builtin_amdgcn_mfma_f32_16x16x32_bf16(pf, vf[dt], o_acc[mt][dt], 0, 0, 0);
            }
        }
    }

    // ---- merge 4 waves' partial (m, l, O) ----
    if (col == 0)
        for (int mt = 0; mt < 4; mt++)
            for (int r = 0; r < 4; r++) {
                int row = mt * 16 + quad * 4 + r;
                sm[wave][row] = m_run[mt][r];
                sl[wave][row] = l_run[mt][r];
            }
    __syncthreads();
    for (int mt = 0; mt < 4; mt++)
        for (int r = 0; r < 4; r++) {
            int row = mt * 16 + quad * 4 + r;
            float M = fmaxf(fmaxf(sm[0][row], sm[1][row]), fmaxf(sm[2][row], sm[3][row]));
            float L = sl[0][row] * __expf(sm[0][row] - M) + sl[1][row] * __expf(sm[1][row] - M)
                    + sl[2][row] * __expf(sm[2][row] - M) + sl[3][row] * __expf(sm[3][row] - M);
            float sc = __expf(m_run[mt][r] - M) / L;
            for (int dt = 0; dt < 4; dt++) o_acc[mt][dt][r] *= sc;
        }
    for (int i = tid; i < 64 * 64; i += 256) oacc[i] = 0.f;
    __syncthreads();
    for (int w = 0; w < 4; w++) {
        if (wave == w)
            for (int mt = 0; mt < 4; mt++)
                for (int dt = 0; dt < 4; dt++)
                    for (int r = 0; r < 4; r++)
                        oacc[(mt * 16 + quad * 4 + r) * 64 + dt * 16 + col] += o_acc[mt][dt][r];
        __syncthreads();
    }
    for (int i = tid; i < 64 * 64; i += 256) {
        int row = i >> 6, c = i & 63;
        AttO[(size_t)(bt * 64 + row) * 512 + h * 64 + c] = f2bf(oacc[i]);
    }
}

// ---------- launch ----------
extern "C" void kernel_launch(void* const* d_in, const int* in_sizes, int n_in,
                              void* d_out, int out_size, void* d_ws, size_t ws_size,
                              hipStream_t stream)
{
    const float* x   = (const float*)d_in[0];
    const float* lat = (const float*)d_in[1];
    const float* g_x = (const float*)d_in[2];
    const float* b_x = (const float*)d_in[3];
    const float* g_l = (const float*)d_in[4];
    const float* b_l = (const float*)d_in[5];
    const float* Wq  = (const float*)d_in[6];
    const float* Wkv = (const float*)d_in[7];
    const float* Wo  = (const float*)d_in[8];
    float* out = (float*)d_out;

    char* ws = (char*)d_ws;
    size_t off = 0;
    auto alloc = [&](size_t bytes) { char* p = ws + off; off += (bytes + 255) & ~(size_t)255; return p; };
    short* A_kvin = (short*)alloc(33792ull * 1024 * 2);  // 69.2 MB (later reused as Vt)
    short* Lq     = (short*)alloc(1024ull * 1024 * 2);
    short* WkvT   = (short*)alloc(1024ull * 1024 * 2);
    short* WqT    = (short*)alloc(512ull * 1024 * 2);
    short* WoT    = (short*)alloc(1024ull * 512 * 2);
    short* KVb    = (short*)alloc(33792ull * 1024 * 2);  // 69.2 MB
    short* Qb     = (short*)alloc(1024ull * 512 * 2);
    short* AttO   = (short*)alloc(1024ull * 512 * 2);
    short* Vt     = A_kvin;  // alias: A_kvin dead after the two input GEMMs

    conv_weights<<<8192, 256, 0, stream>>>(Wq, Wkv, Wo, WqT, WkvT, WoT);
    ln_kernel<<<33792, 256, 0, stream>>>(x, lat, g_x, b_x, g_l, b_l, A_kvin, Lq);
    gemm_bt<short><<<dim3(264, 8), 256, 0, stream>>>(A_kvin, WkvT, KVb, 33792, 1024, 1024);
    gemm_bt<short><<<dim3(8, 4), 256, 0, stream>>>(Lq, WqT, Qb, 1024, 512, 1024);
    transpose_v<<<dim3(66, 2, 128), dim3(32, 8), 0, stream>>>(KVb, Vt);
    attn_kernel<<<128, 256, 0, stream>>>(Qb, KVb, Vt, AttO);
    gemm_bt<float><<<dim3(8, 8), 256, 0, stream>>>(AttO, WoT, out, 1024, 1024, 512);
}

// Round 2
// 420.033 us; speedup vs baseline: 1.0691x; 1.0691x over previous
//
#include <hip/hip_runtime.h>
#include <cstdint>
#include <cstddef>

// ---------- types ----------
typedef __attribute__((ext_vector_type(8))) short short8;   // 8 bf16 (4 VGPRs)
typedef __attribute__((ext_vector_type(4))) short short4v;  // 4 bf16
typedef __attribute__((ext_vector_type(4))) float f32x4;    // MFMA accum

__device__ __forceinline__ short f2bf(float f) {
    union { float f; unsigned u; } c; c.f = f;
    unsigned r = c.u + 0x7fffu + ((c.u >> 16) & 1u);   // RNE
    return (short)(r >> 16);
}

// async global->LDS, 16B per lane; LDS dest must be wave-uniform base + lane*16
__device__ __forceinline__ void gl2lds16(const void* g, void* l) {
    __builtin_amdgcn_global_load_lds(
        (const __attribute__((address_space(1))) void*)g,
        (__attribute__((address_space(3))) void*)l, 16, 0, 0);
}

// ---------- 1. weight convert/transpose (bf16) via LDS tile (coalesced) ----------
// S: (K x N) f32 row-major  ->  D: (N x K) bf16 row-major, D[n][k] = S[k][n]*scale
__global__ __launch_bounds__(256) void wconv(
    const float* __restrict__ S, short* __restrict__ D, int K, int N, float scale)
{
    __shared__ float t[32][33];
    const int kt = blockIdx.x * 32, nt = blockIdx.y * 32;
    const int x = threadIdx.x & 31, y4 = (threadIdx.x >> 5) * 4;
    for (int i = 0; i < 4; i++)
        t[y4 + i][x] = S[(size_t)(kt + y4 + i) * N + nt + x];
    __syncthreads();
    for (int i = 0; i < 4; i++)
        D[(size_t)(nt + y4 + i) * K + kt + x] = f2bf(t[x][y4 + i] * scale);
}

// ---------- 2. LayerNorm -> bf16; builds kv_in = concat(xn, ln) per bt ----------
__global__ __launch_bounds__(256) void ln_kernel(
    const float* __restrict__ x, const float* __restrict__ lat,
    const float* __restrict__ gx, const float* __restrict__ bx,
    const float* __restrict__ gl, const float* __restrict__ bl,
    short* __restrict__ Aout, short* __restrict__ Lq)
{
    const int blk = blockIdx.x;
    const int tid = threadIdx.x;
    const float *src, *g, *b; size_t drow; short* dst2 = nullptr;
    if (blk < 32768) {
        int bt = blk >> 11, i = blk & 2047;
        src = x + (size_t)blk * 1024; g = gx; b = bx;
        drow = (size_t)bt * 2112 + i;
    } else {
        int idx = blk - 32768;
        int bt = idx >> 6, i = idx & 63;
        src = lat + (size_t)idx * 1024; g = gl; b = bl;
        drow = (size_t)bt * 2112 + 2048 + i;
        dst2 = Lq + (size_t)idx * 1024;
    }
    float4 v = ((const float4*)src)[tid];
    float s  = v.x + v.y + v.z + v.w;
    float s2 = v.x * v.x + v.y * v.y + v.z * v.z + v.w * v.w;
    for (int off = 32; off >= 1; off >>= 1) { s += __shfl_down(s, off); s2 += __shfl_down(s2, off); }
    __shared__ float red[8];
    const int wv = tid >> 6, ln_ = tid & 63;
    if (ln_ == 0) { red[wv] = s; red[4 + wv] = s2; }
    __syncthreads();
    s  = red[0] + red[1] + red[2] + red[3];
    s2 = red[4] + red[5] + red[6] + red[7];
    const float mu   = s * (1.f / 1024.f);
    const float var  = s2 * (1.f / 1024.f) - mu * mu;
    const float rstd = rsqrtf(var + 1e-5f);
    float4 gv = ((const float4*)g)[tid];
    float4 bv = ((const float4*)b)[tid];
    short4v o;
    o[0] = f2bf((v.x - mu) * rstd * gv.x + bv.x);
    o[1] = f2bf((v.y - mu) * rstd * gv.y + bv.y);
    o[2] = f2bf((v.z - mu) * rstd * gv.z + bv.z);
    o[3] = f2bf((v.w - mu) * rstd * gv.w + bv.w);
    *(short4v*)(Aout + drow * 1024 + tid * 4) = o;
    if (dst2) *(short4v*)(dst2 + tid * 4) = o;
}

// ---------- 3. bf16 GEMM, C = A(MxK) * Bt(NxK)^T, 128x128 tile, m97 staging ----------
template <typename OutT>
__global__ __launch_bounds__(256) void gemm_bt(
    const short* __restrict__ A, const short* __restrict__ Bt,
    OutT* __restrict__ C, int M, int N, int K)
{
    __shared__ short As[128 * 32];
    __shared__ short Bs[128 * 32];
    const int tid  = threadIdx.x;
    const int wave = tid >> 6, lane = tid & 63;
    const int col  = lane & 15, quad = lane >> 4;
    const int m0 = blockIdx.x * 128, n0 = blockIdx.y * 128;
    const int wm = (wave >> 1) * 64, wn = (wave & 1) * 64;
    const int sr = tid >> 2;           // staging row 0..63
    const int sk = (tid & 3) * 8;      // staging k offset
    // LDS byte offset of &As[sr*32+sk] == tid*16 -> contiguous per lane (DMA-legal)

    f32x4 acc[4][4];
    for (int i = 0; i < 4; i++) for (int j = 0; j < 4; j++) acc[i][j] = f32x4{0.f, 0.f, 0.f, 0.f};

    const short* Ar0 = A  + (size_t)(m0 + sr)      * K + sk;
    const short* Ar1 = A  + (size_t)(m0 + sr + 64) * K + sk;
    const short* Br0 = Bt + (size_t)(n0 + sr)      * K + sk;
    const short* Br1 = Bt + (size_t)(n0 + sr + 64) * K + sk;
    short* lA0 = &As[sr * 32 + sk];
    short* lA1 = &As[(sr + 64) * 32 + sk];
    short* lB0 = &Bs[sr * 32 + sk];
    short* lB1 = &Bs[(sr + 64) * 32 + sk];

    for (int k0 = 0; k0 < K; k0 += 32) {
        __syncthreads();
        gl2lds16(Ar0 + k0, lA0);
        gl2lds16(Ar1 + k0, lA1);
        gl2lds16(Br0 + k0, lB0);
        gl2lds16(Br1 + k0, lB1);
        __syncthreads();
        short8 af[4], bf[4];
        for (int mt = 0; mt < 4; mt++) af[mt] = *(const short8*)&As[(wm + mt * 16 + col) * 32 + quad * 8];
        for (int nt = 0; nt < 4; nt++) bf[nt] = *(const short8*)&Bs[(wn + nt * 16 + col) * 32 + quad * 8];
        for (int mt = 0; mt < 4; mt++)
            for (int nt = 0; nt < 4; nt++)
                acc[mt][nt] = __builtin_amdgcn_mfma_f32_16x16x32_bf16(af[mt], bf[nt], acc[mt][nt], 0, 0, 0);
    }
    for (int mt = 0; mt < 4; mt++)
        for (int nt = 0; nt < 4; nt++)
            for (int r = 0; r < 4; r++) {
                int row = m0 + wm + mt * 16 + quad * 4 + r;
                int cc  = n0 + wn + nt * 16 + col;
                float v = acc[mt][nt][r];
                if constexpr (sizeof(OutT) == 2) C[(size_t)row * N + cc] = (OutT)f2bf(v);
                else                             C[(size_t)row * N + cc] = v;
            }
}

// ---------- 4. transpose V: KV[bt*2112+j][512+h*64+d] -> Vt[(bt*8+h)*64+d][j] ----------
// 64x64 tiles, 16B/lane global both ways; LDS pitch 68 (8B-aligned stores, ~4-way rd)
__global__ __launch_bounds__(256) void transpose_v(const short* __restrict__ KV, short* __restrict__ Vt)
{
    __shared__ short tile[64 * 68];
    const int bth = blockIdx.y, bt = bth >> 3, h = bth & 7;
    const int jt = blockIdx.x * 64;
    const int tid = threadIdx.x;
    for (int it = 0; it < 2; ++it) {
        int s = tid + it * 256;
        int j = s >> 3, dv = (s & 7) * 8;
        short8 v = *(const short8*)(KV + (size_t)(bt * 2112 + jt + j) * 1024 + 512 + h * 64 + dv);
        short4v lo = {v[0], v[1], v[2], v[3]}, hi = {v[4], v[5], v[6], v[7]};
        *(short4v*)&tile[j * 68 + dv]     = lo;
        *(short4v*)&tile[j * 68 + dv + 4] = hi;
    }
    __syncthreads();
    for (int it = 0; it < 2; ++it) {
        int s = tid + it * 256;
        int d = s >> 3, jv = (s & 7) * 8;
        short8 o;
        for (int jj = 0; jj < 8; jj++) o[jj] = tile[(jv + jj) * 68 + d];
        *(short8*)(Vt + (size_t)(bth * 64 + d) * 2112 + jt + jv) = o;
    }
}

// ---------- 5. attention: grid (128 wg, 4 chunks); un-normalized partials ----------
__global__ __launch_bounds__(256) void attn_kernel(
    const short* __restrict__ Q,    // (1024, 512)
    const short* __restrict__ KV,   // (33792, 1024) k in cols 0..511
    const short* __restrict__ Vt,   // (128*64, 2112)
    float* __restrict__ Opart,      // (512, 64, 64)
    float* __restrict__ Mp,         // (512, 64)
    float* __restrict__ Lp)         // (512, 64)
{
    __shared__ short p_lds[4][64 * 72];
    __shared__ float sm[4][64];
    __shared__ float sl[4][64];
    __shared__ float oacc[64 * 64];

    const int wg = blockIdx.x;            // 0..127 = bt*8 + h
    const int ck = blockIdx.y;            // chunk 0..3
    const int wgc = wg * 4 + ck;
    const int bt = wg >> 3, h = wg & 7;
    const int tid = threadIdx.x;
    const int wave = tid >> 6, lane = tid & 63;
    const int col = lane & 15, quad = lane >> 4;

    short8 qf[4][2];
    for (int mt = 0; mt < 4; mt++)
        for (int ks = 0; ks < 2; ks++)
            qf[mt][ks] = *(const short8*)(Q + (size_t)(bt * 64 + mt * 16 + col) * 512
                                            + h * 64 + ks * 32 + quad * 8);

    float m_run[4][4], l_run[4][4];
    f32x4 o_acc[4][4];
    for (int mt = 0; mt < 4; mt++)
        for (int r = 0; r < 4; r++) { m_run[mt][r] = -__builtin_inff(); l_run[mt][r] = 0.f; }
    for (int mt = 0; mt < 4; mt++)
        for (int dt = 0; dt < 4; dt++) o_acc[mt][dt] = f32x4{0.f, 0.f, 0.f, 0.f};

    short* pl = p_lds[wave];

    // 33 key-blocks split over 16 (chunk,wave) pairs: p, p+16, p+32
    for (int jb = ck * 4 + wave; jb < 33; jb += 16) {
        f32x4 s[4][4];
        for (int mt = 0; mt < 4; mt++) for (int nt = 0; nt < 4; nt++) s[mt][nt] = f32x4{0.f, 0.f, 0.f, 0.f};
        for (int nt = 0; nt < 4; nt++) {
            const int j = jb * 64 + nt * 16 + col;
            const short* kp = KV + (size_t)(bt * 2112 + j) * 1024 + h * 64 + quad * 8;
            short8 k0 = *(const short8*)kp;
            short8 k1 = *(const short8*)(kp + 32);
            for (int mt = 0; mt < 4; mt++) {
                s[mt][nt] = __builtin_amdgcn_mfma_f32_16x16x32_bf16(qf[mt][0], k0, s[mt][nt], 0, 0, 0);
                s[mt][nt] = __builtin_amdgcn_mfma_f32_16x16x32_bf16(qf[mt][1], k1, s[mt][nt], 0, 0, 0);
            }
        }
        for (int mt = 0; mt < 4; mt++)
            for (int r = 0; r < 4; r++) {
                float mx = fmaxf(fmaxf(s[mt][0][r], s[mt][1][r]), fmaxf(s[mt][2][r], s[mt][3][r]));
                for (int off = 8; off >= 1; off >>= 1) mx = fmaxf(mx, __shfl_xor(mx, off));
                float mnew = fmaxf(m_run[mt][r], mx);
                float alpha = __expf(m_run[mt][r] - mnew);
                float rs = 0.f;
                for (int nt = 0; nt < 4; nt++) {
                    float p = __expf(s[mt][nt][r] - mnew);
                    s[mt][nt][r] = p;
                    rs += p;
                }
                for (int off = 8; off >= 1; off >>= 1) rs += __shfl_xor(rs, off);
                m_run[mt][r] = mnew;
                l_run[mt][r] = l_run[mt][r] * alpha + rs;
                for (int dt = 0; dt < 4; dt++) o_acc[mt][dt][r] *= alpha;
            }
        for (int mt = 0; mt < 4; mt++)
            for (int nt = 0; nt < 4; nt++)
                for (int r = 0; r < 4; r++)
                    pl[(mt * 16 + quad * 4 + r) * 72 + nt * 16 + col] = f2bf(s[mt][nt][r]);
        for (int ks = 0; ks < 2; ks++) {
            short8 vf[4];
            for (int dt = 0; dt < 4; dt++)
                vf[dt] = *(const short8*)(Vt + (size_t)(wg * 64 + dt * 16 + col) * 2112
                                             + jb * 64 + ks * 32 + quad * 8);
            for (int mt = 0; mt < 4; mt++) {
                short8 pf = *(const short8*)(pl + (mt * 16 + col) * 72 + ks * 32 + quad * 8);
                for (int dt = 0; dt < 4; dt++)
                    o_acc[mt][dt] = __builtin_amdgcn_mfma_f32_16x16x32_bf16(pf, vf[dt], o_acc[mt][dt], 0, 0, 0);
            }
        }
    }

    // ---- merge 4 waves; emit UN-normalized partial (O~, M, L) for this chunk ----
    if (col == 0)
        for (int mt = 0; mt < 4; mt++)
            for (int r = 0; r < 4; r++) {
                int row = mt * 16 + quad * 4 + r;
                sm[wave][row] = m_run[mt][r];
                sl[wave][row] = l_run[mt][r];
            }
    __syncthreads();
    for (int mt = 0; mt < 4; mt++)
        for (int r = 0; r < 4; r++) {
            int row = mt * 16 + quad * 4 + r;
            float M = fmaxf(fmaxf(sm[0][row], sm[1][row]), fmaxf(sm[2][row], sm[3][row]));
            float L = sl[0][row] * __expf(sm[0][row] - M) + sl[1][row] * __expf(sm[1][row] - M)
                    + sl[2][row] * __expf(sm[2][row] - M) + sl[3][row] * __expf(sm[3][row] - M);
            if (wave == 0 && col == 0) { Mp[wgc * 64 + row] = M; Lp[wgc * 64 + row] = L; }
            float sc = __expf(m_run[mt][r] - M);
            for (int dt = 0; dt < 4; dt++) o_acc[mt][dt][r] *= sc;
        }
    for (int i = tid; i < 64 * 64; i += 256) oacc[i] = 0.f;
    __syncthreads();
    for (int w = 0; w < 4; w++) {
        if (wave == w)
            for (int mt = 0; mt < 4; mt++)
                for (int dt = 0; dt < 4; dt++)
                    for (int r = 0; r < 4; r++)
                        oacc[(mt * 16 + quad * 4 + r) * 64 + dt * 16 + col] += o_acc[mt][dt][r];
        __syncthreads();
    }
    for (int i = tid; i < 64 * 64; i += 256)
        Opart[(size_t)wgc * 4096 + i] = oacc[i];
}

// ---------- 6. merge chunk partials -> AttO (bf16) ----------
__global__ __launch_bounds__(256) void attn_merge(
    const float* __restrict__ Opart, const float* __restrict__ Mp,
    const float* __restrict__ Lp, short* __restrict__ AttO)
{
    int idx = blockIdx.x * 256 + threadIdx.x;  // 128*64*64
    int wg = idx >> 12, rd = idx & 4095, row = rd >> 6, d = rd & 63;
    float M = -__builtin_inff();
    for (int c = 0; c < 4; c++) M = fmaxf(M, Mp[(wg * 4 + c) * 64 + row]);
    float L = 0.f, O = 0.f;
    for (int c = 0; c < 4; c++) {
        float e = __expf(Mp[(wg * 4 + c) * 64 + row] - M);
        L += e * Lp[(wg * 4 + c) * 64 + row];
        O += e * Opart[(size_t)(wg * 4 + c) * 4096 + rd];
    }
    int bt = wg >> 3, h = wg & 7;
    AttO[(size_t)(bt * 64 + row) * 512 + h * 64 + d] = f2bf(O / L);
}

// ---------- launch ----------
extern "C" void kernel_launch(void* const* d_in, const int* in_sizes, int n_in,
                              void* d_out, int out_size, void* d_ws, size_t ws_size,
                              hipStream_t stream)
{
    const float* x   = (const float*)d_in[0];
    const float* lat = (const float*)d_in[1];
    const float* g_x = (const float*)d_in[2];
    const float* b_x = (const float*)d_in[3];
    const float* g_l = (const float*)d_in[4];
    const float* b_l = (const float*)d_in[5];
    const float* Wq  = (const float*)d_in[6];
    const float* Wkv = (const float*)d_in[7];
    const float* Wo  = (const float*)d_in[8];
    float* out = (float*)d_out;

    char* ws = (char*)d_ws;
    size_t off = 0;
    auto alloc = [&](size_t bytes) { char* p = ws + off; off += (bytes + 255) & ~(size_t)255; return p; };
    short* A_kvin = (short*)alloc(33792ull * 1024 * 2);  // 69.2 MB; dead after GEMMs -> reused
    short* Lq     = (short*)alloc(1024ull * 1024 * 2);
    short* WkvT   = (short*)alloc(1024ull * 1024 * 2);
    short* WqT    = (short*)alloc(512ull * 1024 * 2);
    short* WoT    = (short*)alloc(1024ull * 512 * 2);
    short* KVb    = (short*)alloc(33792ull * 1024 * 2);  // 69.2 MB
    short* Qb     = (short*)alloc(1024ull * 512 * 2);
    short* AttO   = (short*)alloc(1024ull * 512 * 2);
    // reuse A_kvin region: Vt = 34,603,008 B; partials carved past 36 MiB mark
    short* Vt    = A_kvin;
    char*  sc2   = (char*)A_kvin + 36ull * 1024 * 1024;
    float* Opart = (float*)sc2;                       // 8,388,608 B
    float* Mp    = (float*)(sc2 + 8388608);           // 131,072 B
    float* Lp    = (float*)(sc2 + 8388608 + 131072);  // 131,072 B (ends < 69.2 MB)

    wconv<<<dim3(32, 32), 256, 0, stream>>>(Wkv, WkvT, 1024, 1024, 1.0f);
    wconv<<<dim3(32, 16), 256, 0, stream>>>(Wq,  WqT,  1024, 512,  0.125f);
    wconv<<<dim3(16, 32), 256, 0, stream>>>(Wo,  WoT,  512,  1024, 1.0f);
    ln_kernel<<<33792, 256, 0, stream>>>(x, lat, g_x, b_x, g_l, b_l, A_kvin, Lq);
    gemm_bt<short><<<dim3(264, 8), 256, 0, stream>>>(A_kvin, WkvT, KVb, 33792, 1024, 1024);
    gemm_bt<short><<<dim3(8, 4), 256, 0, stream>>>(Lq, WqT, Qb, 1024, 512, 1024);
    transpose_v<<<dim3(33, 128), 256, 0, stream>>>(KVb, Vt);
    attn_kernel<<<dim3(128, 4), 256, 0, stream>>>(Qb, KVb, Vt, Opart, Mp, Lp);
    attn_merge<<<2048, 256, 0, stream>>>(Opart, Mp, Lp, AttO);
    gemm_bt<float><<<dim3(8, 8), 256, 0, stream>>>(AttO, WoT, out, 1024, 1024, 512);
}